// Round 16
// baseline (6993.552 us; speedup 1.0000x reference)
//
#include <hip/hip_runtime.h>
#include <math.h>

#define KSTEPS  256
#define DMODEL  1024
#define NLAYER  4
#define NTHREADS 1024
#define NBLOCKS 128
#define JPB     32
#define SEQ0_FLOATS (KSTEPS*DMODEL)            // 1 MB
#define INITFLAG_INTS (256*32)                 // 32 KB
#define REC_OFF_FLOATS (SEQ0_FLOATS + INITFLAG_INTS)
#define REC_ULL ((size_t)NLAYER*KSTEPS*DMODEL) // 8 MB of 8B packets
#define WS_NEED_BYTES ((size_t)REC_OFF_FLOATS*4 + REC_ULL*8)
#define TIME_CAP 5000000LL                     // ~50ms backstop

typedef float f32x4 __attribute__((ext_vector_type(4)));
typedef unsigned long long u64;

__device__ __forceinline__ u64 ld_pkt(const u64* p) {
  return __hip_atomic_load(p, __ATOMIC_RELAXED, __HIP_MEMORY_SCOPE_AGENT);
}
__device__ __forceinline__ void st_pkt(u64* p, u64 v) {
  __hip_atomic_store(p, v, __ATOMIC_RELAXED, __HIP_MEMORY_SCOPE_AGENT);
}
__device__ __forceinline__ void st_agent(float* p, float v) {
  __hip_atomic_store(p, v, __ATOMIC_RELAXED, __HIP_MEMORY_SCOPE_AGENT);
}

// wave64 sum via DPP (VALU pipe only); result valid in lane 63
#define DPP_STEP(v, ctrl) \
  v += __builtin_bit_cast(float, __builtin_amdgcn_update_dpp( \
        0, __builtin_bit_cast(int, v), ctrl, 0xf, 0xf, true))
__device__ __forceinline__ float wave_sum64(float v) {
  DPP_STEP(v, 0x111);  // row_shr:1
  DPP_STEP(v, 0x112);  // row_shr:2
  DPP_STEP(v, 0x114);  // row_shr:4
  DPP_STEP(v, 0x118);  // row_shr:8
  DPP_STEP(v, 0x142);  // row_bcast:15
  DPP_STEP(v, 0x143);  // row_bcast:31
  return v;
}

__device__ __forceinline__ float tanh_fast(float s) {
  float e = __expf(2.f * s);
  return 1.f - 2.f / (e + 1.f);   // inf-safe
}

// zero rec (blocks 0..1023); initflags (block 1024)
__global__ void cfc_init(int* initflags, u64* rec) {
  if (blockIdx.x < 1024) {
    rec[(size_t)blockIdx.x * 1024 + threadIdx.x] = 0ULL;
  } else {
    int j = threadIdx.x;
    #pragma unroll
    for (int q = 0; q < 8; ++q) initflags[j * 8 + q] = 0;
  }
}

__global__ __launch_bounds__(NTHREADS, 1)
void cfc_main(const float* __restrict__ sensor_vals,   // [256][3]
              const float* __restrict__ sensor_pos,    // [256][2]
              const float* __restrict__ Bm,            // [2][256]
              const float* __restrict__ proj_w,        // [515][1024]
              const float* __restrict__ proj_b,        // [1024]
              const float* __restrict__ ff1_w, const float* __restrict__ ff1_b,
              const float* __restrict__ ff2_w, const float* __restrict__ ff2_b,
              const float* __restrict__ ta_w,  const float* __restrict__ ta_b,
              const float* __restrict__ tb_w,  const float* __restrict__ tb_b,
              float* __restrict__ out,                 // [1024]
              float* __restrict__ ws)
{
  __shared__ float smem[16384];   // 64KB: phase-1 slabs; scan uses [0,4096)

  const long long tstart = __builtin_amdgcn_s_memrealtime();
  const int tid   = threadIdx.x;
  const int bid   = blockIdx.x;
  const int layer = bid & 3;            // XCD-affinity: layer l -> XCDs {l, l+4}
  const int slot  = bid >> 2;           // 0..31
  const int w     = tid >> 6;           // wave 0..15 -> cols j0+2w, j0+2w+1
  const int lane  = tid & 63;           // lane l -> rows {256q + 4l + j}
  const int j0    = slot * JPB;

  float*    seq0      = ws;                               // [256][1024]
  int*      initflags = (int*)(ws + SEQ0_FLOATS);         // [128] stride 32
  u64*      rec       = (u64*)(ws + REC_OFF_FLOATS);      // [4][256][1024]

  // ---------------- phase 0: seq0 = RFF-proj (each block: 8 cols, all t) -----
  {
    int t  = tid & 255;
    int jp = tid >> 8;                  // 0..3
    int jj = bid * 8 + jp * 2;          // 128 blocks x 8 = 1024 cols
    float p0 = sensor_pos[t*2+0], p1 = sensor_pos[t*2+1];
    float a0 = 0.f, a1 = 0.f;
    for (int r = 0; r < 256; ++r) {
      float pr = p0 * Bm[r] + p1 * Bm[256 + r];
      float sn, cs;
      __sincosf(pr, &sn, &cs);
      a0 += cs * proj_w[r*1024 + jj]     + sn * proj_w[(256+r)*1024 + jj];
      a1 += cs * proj_w[r*1024 + jj + 1] + sn * proj_w[(256+r)*1024 + jj + 1];
    }
    for (int i = 0; i < 3; ++i) {
      float v = sensor_vals[t*3 + i];
      a0 += v * proj_w[(512+i)*1024 + jj];
      a1 += v * proj_w[(512+i)*1024 + jj + 1];
    }
    a0 += proj_b[jj]; a1 += proj_b[jj + 1];
    st_agent(&seq0[t*DMODEL + jj],     a0);
    st_agent(&seq0[t*DMODEL + jj + 1], a1);
    __syncthreads();
    if (tid == 0)
      __hip_atomic_store(&initflags[bid*32], 1, __ATOMIC_RELEASE, __HIP_MEMORY_SCOPE_AGENT);
  }

  // ---------------- phase 1: weights into VGPRs ------------------------------
  // wave w owns cols {j0+2w, j0+2w+1}; lane l owns rows {256q+4l+j}, k=4q+j
  // 16 phases: p=mat(2b) | hf=x/h half | ch=col half (16-col slab each)
  // slab: smem[c*1024 + ((row + 4c) & 1023)]; rotation cancels on read
  float wx[3][2][16], wh[3][2][16];
  {
    const float* mats[4] = { ff1_w + (size_t)layer*2048*DMODEL,
                             ff2_w + (size_t)layer*2048*DMODEL,
                             ta_w  + (size_t)layer*2048*DMODEL,
                             tb_w  + (size_t)layer*2048*DMODEL };
    #pragma unroll
    for (int ph = 0; ph < 16; ++ph) {
      const int p  = ph >> 2;           // mat 0..3
      const int hf = (ph >> 1) & 1;     // row half: 0=x, 1=h
      const int ch = ph & 1;            // col half: 0=cols 0-15, 1=cols 16-31
      __syncthreads();
      const float* W = mats[p];
      for (int i = 0; i < 8; ++i) {     // 8 x 1024 thr x 2 floats = 16K slab
        int f0 = (i*1024 + tid) * 2;
        int rl = f0 >> 4;               // 0..1023
        int c  = f0 & 15;               // even local col
        float2 v = *(const float2*)&W[(size_t)(hf*1024 + rl)*DMODEL
                                      + j0 + ch*16 + c];
        smem[ c   *1024 + ((rl + 4* c   ) & 1023)] = v.x;
        smem[(c+1)*1024 + ((rl + 4*(c+1)) & 1023)] = v.y;
      }
      __syncthreads();
      if ((w >> 3) == ch) {             // waves owning this col half
        #pragma unroll
        for (int cc = 0; cc < 2; ++cc) {
          const int c = 2*(w & 7) + cc; // local col in slab
          #pragma unroll
          for (int q = 0; q < 4; ++q) {
            int rowbase = (256*q + 4*lane + 4*c) & 1023;
            f32x4 v = *(const f32x4*)&smem[c*1024 + rowbase];
            #pragma unroll
            for (int j = 0; j < 4; ++j) {
              const int k = 4*q + j;
              float vv = v[j];
              if      (p == 0) { if (hf == 0) wx[0][cc][k] = vv;  else wh[0][cc][k] = vv; }
              else if (p == 1) { if (hf == 0) wx[1][cc][k] = vv;  else wh[1][cc][k] = vv; }
              else if (p == 2) { if (hf == 0) wx[2][cc][k] = -vv; else wh[2][cc][k] = -vv; }
              else             { if (hf == 0) wx[2][cc][k] += vv; else wh[2][cc][k] += vv; }
            }
          }
        }
      }
    }
  }
  float bb1[2], bb2[2], bbc[2];
  #pragma unroll
  for (int cc = 0; cc < 2; ++cc) {
    int j = j0 + 2*w + cc;
    bb1[cc] = ff1_b[layer*DMODEL + j];
    bb2[cc] = ff2_b[layer*DMODEL + j];
    bbc[cc] = tb_b[layer*DMODEL + j] - ta_b[layer*DMODEL + j];
  }

  // ---------------- wait for seq0 (layer 0 only) -----------------------------
  if (layer == 0) {
    if (tid < 64) {
      for (;;) {
        int ok = 1;
        for (int q = 0; q < 2; ++q) {
          int v = __hip_atomic_load(&initflags[(tid + q*64)*32],
                                    __ATOMIC_RELAXED, __HIP_MEMORY_SCOPE_AGENT);
          ok &= (v != 0);
        }
        if (__all(ok)) break;
        if (__builtin_amdgcn_s_memrealtime() - tstart > TIME_CAP) break;
      }
      __threadfence();
    }
  }
  __syncthreads();

  // ---------------- phase 2: wavefront scan ----------------------------------
  // sole sync mechanism: self-validating stamped packets, sticky per-packet spin
  u64* recO = rec + (size_t)layer * KSTEPS * DMODEL;
  u64* recP = rec + (size_t)(layer > 0 ? layer-1 : 0) * KSTEPS * DMODEL;

  for (int t = 0; t < KSTEPS; ++t) {
    const int needH = (t > 0);
    const int needX = (layer > 0);

    // ---- data gather: 1 h + 1 x packet per thread, sticky spin
    const int i0 = tid;
    float hv = 0.f, xv = 0.f;
    if (layer == 0) {
      xv = seq0[(size_t)t*DMODEL + i0];
    }
    if (needH | needX) {
      const u64* pH = recO + (needH ? (size_t)(t-1)*DMODEL : 0) + i0;
      const u64* pX = recP + (size_t)t*DMODEL + i0;
      const unsigned sh = (unsigned)t, sx = (unsigned)(t + 1);
      int hok = !needH, xok = !needX;
      u64 h0 = 0, x0 = 0;
      int c3 = 0;
      for (;;) {
        if (!hok) { h0 = ld_pkt(pH);
                    hok = ((unsigned)(h0 >> 32) == sh); }
        if (!xok) { x0 = ld_pkt(pX);
                    xok = ((unsigned)(x0 >> 32) == sx); }
        if (__all(hok & xok)) break;
        __builtin_amdgcn_s_sleep(2);
        if (((++c3) & 31) == 0 &&
            __builtin_amdgcn_s_memrealtime() - tstart > TIME_CAP) break;
      }
      if (needH) hv = __int_as_float((int)(unsigned)h0);
      if (needX) xv = __int_as_float((int)(unsigned)x0);
    }

    // ---- stage to LDS (linear, parity double-buffered)
    float* hbuf = smem + (t & 1) * 2048;
    float* xbuf = hbuf + 1024;
    hbuf[i0] = hv;
    xbuf[i0] = xv;
    __syncthreads();   // the single barrier per round

    // ---- FMA: 8x ds_read_b128 (contiguous per instr), 192 fma
    float a[3][2] = {};
    #pragma unroll
    for (int q = 0; q < 4; ++q) {
      f32x4 vh = *(const f32x4*)&hbuf[256*q + 4*lane];
      f32x4 vx = *(const f32x4*)&xbuf[256*q + 4*lane];
      #pragma unroll
      for (int j = 0; j < 4; ++j) {
        const int k = 4*q + j;
        const float xj = vx[j], hj = vh[j];
        #pragma unroll
        for (int m = 0; m < 3; ++m)
          #pragma unroll
          for (int cc = 0; cc < 2; ++cc)
            a[m][cc] = fmaf(xj, wx[m][cc][k], fmaf(hj, wh[m][cc][k], a[m][cc]));
      }
    }

    // ---- wave DPP reduce; lane 63 finalizes 2 cols
    float r[3][2];
    #pragma unroll
    for (int m = 0; m < 3; ++m)
      #pragma unroll
      for (int cc = 0; cc < 2; ++cc)
        r[m][cc] = wave_sum64(a[m][cc]);

    if (lane == 63) {
      #pragma unroll
      for (int cc = 0; cc < 2; ++cc) {
        float f1 = tanh_fast(r[0][cc] + bb1[cc]);
        float f2 = tanh_fast(r[1][cc] + bb2[cc]);
        float g  = 1.f / (1.f + __expf(-(r[2][cc] + bbc[cc])));
        float h  = f2 + g * (f1 - f2);
        int j = j0 + 2*w + cc;
        u64 pk = ((u64)(unsigned)(t + 1) << 32) | (unsigned)__float_as_int(h);
        st_pkt(recO + (size_t)t*DMODEL + j, pk);
        if (layer == NLAYER-1 && t == KSTEPS-1) out[j] = h;
      }
    }
    // no trailing barrier: next round writes the other LDS parity
  }
}

extern "C" void kernel_launch(void* const* d_in, const int* in_sizes, int n_in,
                              void* d_out, int out_size, void* d_ws, size_t ws_size,
                              hipStream_t stream) {
  if (ws_size < WS_NEED_BYTES) return;  // informative fail, no fault

  const float* sensor_vals = (const float*)d_in[0];
  const float* sensor_pos  = (const float*)d_in[1];
  const float* Bm          = (const float*)d_in[2];
  const float* proj_w      = (const float*)d_in[3];
  const float* proj_b      = (const float*)d_in[4];
  const float* ff1_w       = (const float*)d_in[5];
  const float* ff1_b       = (const float*)d_in[6];
  const float* ff2_w       = (const float*)d_in[7];
  const float* ff2_b       = (const float*)d_in[8];
  const float* ta_w        = (const float*)d_in[9];
  const float* ta_b        = (const float*)d_in[10];
  const float* tb_w        = (const float*)d_in[11];
  const float* tb_b        = (const float*)d_in[12];
  float* ws        = (float*)d_ws;
  int* initflags   = (int*)(ws + SEQ0_FLOATS);
  u64* rec         = (u64*)(ws + REC_OFF_FLOATS);

  cfc_init<<<1025, 1024, 0, stream>>>(initflags, rec);
  cfc_main<<<NBLOCKS, NTHREADS, 0, stream>>>(sensor_vals, sensor_pos, Bm,
                                             proj_w, proj_b,
                                             ff1_w, ff1_b, ff2_w, ff2_b,
                                             ta_w, ta_b, tb_w, tb_b,
                                             (float*)d_out, ws);
}

// Round 17
// 641.032 us; speedup vs baseline: 10.9098x; 10.9098x over previous
//
#include <hip/hip_runtime.h>
#include <math.h>

#define KSTEPS  256
#define DMODEL  1024
#define NLAYER  4
#define NTHREADS 512
#define JPB     16
#define SEQ0_FLOATS (KSTEPS*DMODEL)            // 1 MB
#define INITFLAG_INTS (256*32)                 // 32 KB
#define REC_OFF_FLOATS (SEQ0_FLOATS + INITFLAG_INTS)
#define REC_ULL ((size_t)NLAYER*KSTEPS*DMODEL) // 8 MB of 8B packets
#define WS_NEED_BYTES ((size_t)REC_OFF_FLOATS*4 + REC_ULL*8)
#define TIME_CAP 5000000LL                     // ~50ms backstop

typedef float f32x4 __attribute__((ext_vector_type(4)));
typedef unsigned long long u64;

__device__ __forceinline__ u64 ld_pkt(const u64* p) {
  return __hip_atomic_load(p, __ATOMIC_RELAXED, __HIP_MEMORY_SCOPE_AGENT);
}
__device__ __forceinline__ void st_pkt(u64* p, u64 v) {
  __hip_atomic_store(p, v, __ATOMIC_RELAXED, __HIP_MEMORY_SCOPE_AGENT);
}
__device__ __forceinline__ void st_agent(float* p, float v) {
  __hip_atomic_store(p, v, __ATOMIC_RELAXED, __HIP_MEMORY_SCOPE_AGENT);
}

// wave64 sum via DPP (VALU pipe only); result valid in lane 63
#define DPP_STEP(v, ctrl) \
  v += __builtin_bit_cast(float, __builtin_amdgcn_update_dpp( \
        0, __builtin_bit_cast(int, v), ctrl, 0xf, 0xf, true))
__device__ __forceinline__ float wave_sum64(float v) {
  DPP_STEP(v, 0x111);  // row_shr:1
  DPP_STEP(v, 0x112);  // row_shr:2
  DPP_STEP(v, 0x114);  // row_shr:4
  DPP_STEP(v, 0x118);  // row_shr:8
  DPP_STEP(v, 0x142);  // row_bcast:15
  DPP_STEP(v, 0x143);  // row_bcast:31
  return v;
}

__device__ __forceinline__ float tanh_fast(float s) {
  float e = __expf(2.f * s);
  return 1.f - 2.f / (e + 1.f);   // inf-safe
}

// zero rec (blocks 0..1023); initflags (block 1024)
__global__ void cfc_init(int* initflags, u64* rec) {
  if (blockIdx.x < 1024) {
    rec[(size_t)blockIdx.x * 1024 + threadIdx.x] = 0ULL;
  } else {
    int j = threadIdx.x;
    #pragma unroll
    for (int q = 0; q < 8; ++q) initflags[j * 8 + q] = 0;
  }
}

__global__ __launch_bounds__(NTHREADS, 1)
void cfc_main(const float* __restrict__ sensor_vals,   // [256][3]
              const float* __restrict__ sensor_pos,    // [256][2]
              const float* __restrict__ Bm,            // [2][256]
              const float* __restrict__ proj_w,        // [515][1024]
              const float* __restrict__ proj_b,        // [1024]
              const float* __restrict__ ff1_w, const float* __restrict__ ff1_b,
              const float* __restrict__ ff2_w, const float* __restrict__ ff2_b,
              const float* __restrict__ ta_w,  const float* __restrict__ ta_b,
              const float* __restrict__ tb_w,  const float* __restrict__ tb_b,
              float* __restrict__ out,                 // [1024]
              float* __restrict__ ws)
{
  __shared__ float smem[16384];   // 64KB: phase-1 slabs; scan uses [0,4096)

  const long long tstart = __builtin_amdgcn_s_memrealtime();
  const int tid   = threadIdx.x;
  const int bid   = blockIdx.x;
  const int layer = bid & 3;            // XCD-affinity: layer l -> XCDs {l, l+4}
  const int slot  = bid >> 2;           // 0..63
  const int w     = tid >> 6;           // wave -> cols j0+2w, j0+2w+1
  const int lane  = tid & 63;           // lane l -> rows {256q + 4l + j}
  const int j0    = slot * JPB;

  float*    seq0      = ws;                               // [256][1024]
  int*      initflags = (int*)(ws + SEQ0_FLOATS);         // [256] stride 32
  u64*      rec       = (u64*)(ws + REC_OFF_FLOATS);      // [4][256][1024]

  // ---------------- phase 0: seq0 = RFF-proj (each block: 4 cols, all t) -----
  {
    int t  = tid & 255;
    int jp = tid >> 8;
    int jj = bid * 4 + jp * 2;          // bid-based: covers all 1024 cols
    float p0 = sensor_pos[t*2+0], p1 = sensor_pos[t*2+1];
    float a0 = 0.f, a1 = 0.f;
    for (int r = 0; r < 256; ++r) {
      float pr = p0 * Bm[r] + p1 * Bm[256 + r];
      float sn, cs;
      __sincosf(pr, &sn, &cs);
      a0 += cs * proj_w[r*1024 + jj]     + sn * proj_w[(256+r)*1024 + jj];
      a1 += cs * proj_w[r*1024 + jj + 1] + sn * proj_w[(256+r)*1024 + jj + 1];
    }
    for (int i = 0; i < 3; ++i) {
      float v = sensor_vals[t*3 + i];
      a0 += v * proj_w[(512+i)*1024 + jj];
      a1 += v * proj_w[(512+i)*1024 + jj + 1];
    }
    a0 += proj_b[jj]; a1 += proj_b[jj + 1];
    st_agent(&seq0[t*DMODEL + jj],     a0);
    st_agent(&seq0[t*DMODEL + jj + 1], a1);
    __syncthreads();
    if (tid == 0)
      __hip_atomic_store(&initflags[bid*32], 1, __ATOMIC_RELEASE, __HIP_MEMORY_SCOPE_AGENT);
  }

  // ---------------- phase 1: weights into VGPRs ------------------------------
  // wave w owns cols {j0+2w, j0+2w+1}; lane l owns rows {256q+4l+j}, k=4q+j
  // slab: smem[c*1024 + ((row + 4c) & 1023)] -> writes 2-way (free),
  // reads 4x b128 per col, 64 lanes contiguous (conflict-free, 16B aligned)
  float wx[3][2][16], wh[3][2][16];
  {
    const float* mats[4] = { ff1_w + (size_t)layer*2048*DMODEL,
                             ff2_w + (size_t)layer*2048*DMODEL,
                             ta_w  + (size_t)layer*2048*DMODEL,
                             tb_w  + (size_t)layer*2048*DMODEL };
    #pragma unroll
    for (int ph = 0; ph < 8; ++ph) {    // p = ph>>1 (mat), hf = ph&1 (x/h half)
      const int p  = ph >> 1;
      const int hf = ph & 1;
      __syncthreads();
      const float* W = mats[p];
      for (int i = 0; i < 16; ++i) {
        int f0 = (i*512 + tid) * 2;
        int rl = f0 >> 4;
        int c  = f0 & 15;
        float2 v = *(const float2*)&W[(size_t)(hf*1024 + rl)*DMODEL + j0 + c];
        smem[ c   *1024 + ((rl + 4* c   ) & 1023)] = v.x;
        smem[(c+1)*1024 + ((rl + 4*(c+1)) & 1023)] = v.y;
      }
      __syncthreads();
      #pragma unroll
      for (int cc = 0; cc < 2; ++cc) {
        const int c = 2*w + cc;
        #pragma unroll
        for (int q = 0; q < 4; ++q) {
          int rowbase = (256*q + 4*lane + 4*c) & 1023;
          f32x4 v = *(const f32x4*)&smem[c*1024 + rowbase];
          #pragma unroll
          for (int j = 0; j < 4; ++j) {
            const int k = 4*q + j;
            float vv = v[j];
            if      (ph == 0) wx[0][cc][k] = vv;
            else if (ph == 1) wh[0][cc][k] = vv;
            else if (ph == 2) wx[1][cc][k] = vv;
            else if (ph == 3) wh[1][cc][k] = vv;
            else if (ph == 4) wx[2][cc][k] = -vv;
            else if (ph == 5) wh[2][cc][k] = -vv;
            else if (ph == 6) wx[2][cc][k] += vv;
            else              wh[2][cc][k] += vv;
          }
        }
      }
    }
  }
  float bb1[2], bb2[2], bbc[2];
  #pragma unroll
  for (int cc = 0; cc < 2; ++cc) {
    int j = j0 + 2*w + cc;
    bb1[cc] = ff1_b[layer*DMODEL + j];
    bb2[cc] = ff2_b[layer*DMODEL + j];
    bbc[cc] = tb_b[layer*DMODEL + j] - ta_b[layer*DMODEL + j];
  }

  // ---------------- wait for seq0 (layer 0 only) -----------------------------
  if (layer == 0) {
    if (tid < 64) {
      for (;;) {
        int ok = 1;
        for (int q = 0; q < 4; ++q) {
          int v = __hip_atomic_load(&initflags[(tid + q*64)*32],
                                    __ATOMIC_RELAXED, __HIP_MEMORY_SCOPE_AGENT);
          ok &= (v != 0);
        }
        if (__all(ok)) break;
        if (__builtin_amdgcn_s_memrealtime() - tstart > TIME_CAP) break;
      }
      __threadfence();
    }
  }
  __syncthreads();

  // ---------------- phase 2: wavefront scan, split x/h phases ----------------
  u64* recO = rec + (size_t)layer * KSTEPS * DMODEL;
  u64* recP = rec + (size_t)(layer > 0 ? layer-1 : 0) * KSTEPS * DMODEL;

  for (int t = 0; t < KSTEPS; ++t) {
    const int needH = (t > 0);
    const int needX = (layer > 0);
    const int i0 = tid << 1;
    const u64* pH = recO + (needH ? (size_t)(t-1)*DMODEL : 0) + i0;
    const unsigned sh = (unsigned)t;

    // ---- x phase: gather (1-round slack -> usually first-try), stage -------
    float xva = 0.f, xvb = 0.f;
    if (layer == 0) {
      float2 x2 = *(const float2*)&seq0[(size_t)t*DMODEL + i0];
      xva = x2.x; xvb = x2.y;
    } else {
      const u64* pX = recP + (size_t)t*DMODEL + i0;
      const unsigned sx = (unsigned)(t + 1);
      u64 x0 = 0, x1 = 0;
      int xok = 0, c3 = 0;
      for (;;) {
        x0 = ld_pkt(pX); x1 = ld_pkt(pX + 1);
        xok = ((unsigned)(x0 >> 32) == sx) & ((unsigned)(x1 >> 32) == sx);
        if (__all(xok)) break;
        __builtin_amdgcn_s_sleep(2);
        if (((++c3) & 31) == 0 &&
            __builtin_amdgcn_s_memrealtime() - tstart > TIME_CAP) break;
      }
      xva = __int_as_float((int)(unsigned)x0);
      xvb = __int_as_float((int)(unsigned)x1);
    }
    float* hbuf = smem + (t & 1) * 2048;
    float* xbuf = hbuf + 1024;
    *(float2*)&xbuf[i0] = make_float2(xva, xvb);
    __syncthreads();   // B1: xbuf ready

    // ---- early h probe: loads fly during the x-FMAs ------------------------
    u64 h0 = 0, h1 = 0;
    if (needH) { h0 = ld_pkt(pH); h1 = ld_pkt(pH + 1); }

    // ---- x-FMA (96 fma) while h probe is in flight -------------------------
    float a[3][2] = {};
    #pragma unroll
    for (int q = 0; q < 4; ++q) {
      f32x4 vx = *(const f32x4*)&xbuf[256*q + 4*lane];
      #pragma unroll
      for (int j = 0; j < 4; ++j) {
        const int k = 4*q + j;
        const float xj = vx[j];
        #pragma unroll
        for (int m = 0; m < 3; ++m)
          #pragma unroll
          for (int cc = 0; cc < 2; ++cc)
            a[m][cc] = fmaf(xj, wx[m][cc][k], a[m][cc]);
      }
    }

    // ---- h resolve: check early probe, spin only if stale ------------------
    float hva = 0.f, hvb = 0.f;
    if (needH) {
      int hok = ((unsigned)(h0 >> 32) == sh) & ((unsigned)(h1 >> 32) == sh);
      int c4 = 0;
      while (!__all(hok)) {
        __builtin_amdgcn_s_sleep(2);
        if (!hok) { h0 = ld_pkt(pH); h1 = ld_pkt(pH + 1);
                    hok = ((unsigned)(h0 >> 32) == sh) &
                          ((unsigned)(h1 >> 32) == sh); }
        if (((++c4) & 31) == 0 &&
            __builtin_amdgcn_s_memrealtime() - tstart > TIME_CAP) break;
      }
      hva = __int_as_float((int)(unsigned)h0);
      hvb = __int_as_float((int)(unsigned)h1);
    }
    *(float2*)&hbuf[i0] = make_float2(hva, hvb);
    __syncthreads();   // B2: hbuf ready

    // ---- h-FMA (96 fma): short post-detect tail ----------------------------
    #pragma unroll
    for (int q = 0; q < 4; ++q) {
      f32x4 vh = *(const f32x4*)&hbuf[256*q + 4*lane];
      #pragma unroll
      for (int j = 0; j < 4; ++j) {
        const int k = 4*q + j;
        const float hj = vh[j];
        #pragma unroll
        for (int m = 0; m < 3; ++m)
          #pragma unroll
          for (int cc = 0; cc < 2; ++cc)
            a[m][cc] = fmaf(hj, wh[m][cc][k], a[m][cc]);
      }
    }

    // ---- wave DPP reduce; lane 63 finalizes 2 cols
    float r[3][2];
    #pragma unroll
    for (int m = 0; m < 3; ++m)
      #pragma unroll
      for (int cc = 0; cc < 2; ++cc)
        r[m][cc] = wave_sum64(a[m][cc]);

    if (lane == 63) {
      #pragma unroll
      for (int cc = 0; cc < 2; ++cc) {
        float f1 = tanh_fast(r[0][cc] + bb1[cc]);
        float f2 = tanh_fast(r[1][cc] + bb2[cc]);
        float g  = 1.f / (1.f + __expf(-(r[2][cc] + bbc[cc])));
        float h  = f2 + g * (f1 - f2);
        int j = j0 + 2*w + cc;
        u64 pk = ((u64)(unsigned)(t + 1) << 32) | (unsigned)__float_as_int(h);
        st_pkt(recO + (size_t)t*DMODEL + j, pk);
        if (layer == NLAYER-1 && t == KSTEPS-1) out[j] = h;
      }
    }
    // no trailing barrier: next round uses the other LDS parity
  }
}

extern "C" void kernel_launch(void* const* d_in, const int* in_sizes, int n_in,
                              void* d_out, int out_size, void* d_ws, size_t ws_size,
                              hipStream_t stream) {
  if (ws_size < WS_NEED_BYTES) return;  // informative fail, no fault

  const float* sensor_vals = (const float*)d_in[0];
  const float* sensor_pos  = (const float*)d_in[1];
  const float* Bm          = (const float*)d_in[2];
  const float* proj_w      = (const float*)d_in[3];
  const float* proj_b      = (const float*)d_in[4];
  const float* ff1_w       = (const float*)d_in[5];
  const float* ff1_b       = (const float*)d_in[6];
  const float* ff2_w       = (const float*)d_in[7];
  const float* ff2_b       = (const float*)d_in[8];
  const float* ta_w        = (const float*)d_in[9];
  const float* ta_b        = (const float*)d_in[10];
  const float* tb_w        = (const float*)d_in[11];
  const float* tb_b        = (const float*)d_in[12];
  float* ws        = (float*)d_ws;
  int* initflags   = (int*)(ws + SEQ0_FLOATS);
  u64* rec         = (u64*)(ws + REC_OFF_FLOATS);

  cfc_init<<<1025, 1024, 0, stream>>>(initflags, rec);
  cfc_main<<<256, NTHREADS, 0, stream>>>(sensor_vals, sensor_pos, Bm,
                                         proj_w, proj_b,
                                         ff1_w, ff1_b, ff2_w, ff2_b,
                                         ta_w, ta_b, tb_w, tb_b,
                                         (float*)d_out, ws);
}

// Round 18
// 637.591 us; speedup vs baseline: 10.9687x; 1.0054x over previous
//
#include <hip/hip_runtime.h>
#include <math.h>

#define KSTEPS  256
#define DMODEL  1024
#define NLAYER  4
#define NTHREADS 512
#define JPB     16
#define SEQ0_FLOATS (KSTEPS*DMODEL)            // 1 MB
#define INITFLAG_INTS (256*32)                 // 32 KB
#define REC_OFF_FLOATS (SEQ0_FLOATS + INITFLAG_INTS)
#define REC_ULL ((size_t)NLAYER*KSTEPS*DMODEL) // 8 MB of 8B packets
#define WS_NEED_BYTES ((size_t)REC_OFF_FLOATS*4 + REC_ULL*8)
#define TIME_CAP 5000000LL                     // ~50ms backstop

typedef float f32x4 __attribute__((ext_vector_type(4)));
typedef unsigned long long u64;

__device__ __forceinline__ u64 ld_pkt(const u64* p) {
  return __hip_atomic_load(p, __ATOMIC_RELAXED, __HIP_MEMORY_SCOPE_AGENT);
}
// publish via atomic swap: executes AT the coherence point (no write-buffer
// dawdle) — the single change vs r17, targeting store->load visibility
__device__ __forceinline__ void st_pkt(u64* p, u64 v) {
  (void)__hip_atomic_exchange(p, v, __ATOMIC_RELAXED, __HIP_MEMORY_SCOPE_AGENT);
}
__device__ __forceinline__ void st_agent(float* p, float v) {
  __hip_atomic_store(p, v, __ATOMIC_RELAXED, __HIP_MEMORY_SCOPE_AGENT);
}

// wave64 sum via DPP (VALU pipe only); result valid in lane 63
#define DPP_STEP(v, ctrl) \
  v += __builtin_bit_cast(float, __builtin_amdgcn_update_dpp( \
        0, __builtin_bit_cast(int, v), ctrl, 0xf, 0xf, true))
__device__ __forceinline__ float wave_sum64(float v) {
  DPP_STEP(v, 0x111);  // row_shr:1
  DPP_STEP(v, 0x112);  // row_shr:2
  DPP_STEP(v, 0x114);  // row_shr:4
  DPP_STEP(v, 0x118);  // row_shr:8
  DPP_STEP(v, 0x142);  // row_bcast:15
  DPP_STEP(v, 0x143);  // row_bcast:31
  return v;
}

__device__ __forceinline__ float tanh_fast(float s) {
  float e = __expf(2.f * s);
  return 1.f - 2.f / (e + 1.f);   // inf-safe
}

// zero rec (blocks 0..1023); initflags (block 1024)
__global__ void cfc_init(int* initflags, u64* rec) {
  if (blockIdx.x < 1024) {
    rec[(size_t)blockIdx.x * 1024 + threadIdx.x] = 0ULL;
  } else {
    int j = threadIdx.x;
    #pragma unroll
    for (int q = 0; q < 8; ++q) initflags[j * 8 + q] = 0;
  }
}

__global__ __launch_bounds__(NTHREADS, 1)
void cfc_main(const float* __restrict__ sensor_vals,   // [256][3]
              const float* __restrict__ sensor_pos,    // [256][2]
              const float* __restrict__ Bm,            // [2][256]
              const float* __restrict__ proj_w,        // [515][1024]
              const float* __restrict__ proj_b,        // [1024]
              const float* __restrict__ ff1_w, const float* __restrict__ ff1_b,
              const float* __restrict__ ff2_w, const float* __restrict__ ff2_b,
              const float* __restrict__ ta_w,  const float* __restrict__ ta_b,
              const float* __restrict__ tb_w,  const float* __restrict__ tb_b,
              float* __restrict__ out,                 // [1024]
              float* __restrict__ ws)
{
  __shared__ float smem[16384];   // 64KB: phase-1 slabs; scan uses [0,4096)

  const long long tstart = __builtin_amdgcn_s_memrealtime();
  const int tid   = threadIdx.x;
  const int bid   = blockIdx.x;
  const int layer = bid & 3;            // XCD-affinity: layer l -> XCDs {l, l+4}
  const int slot  = bid >> 2;           // 0..63
  const int w     = tid >> 6;           // wave -> cols j0+2w, j0+2w+1
  const int lane  = tid & 63;           // lane l -> rows {256q + 4l + j}
  const int j0    = slot * JPB;

  float*    seq0      = ws;                               // [256][1024]
  int*      initflags = (int*)(ws + SEQ0_FLOATS);         // [256] stride 32
  u64*      rec       = (u64*)(ws + REC_OFF_FLOATS);      // [4][256][1024]

  // ---------------- phase 0: seq0 = RFF-proj (each block: 4 cols, all t) -----
  {
    int t  = tid & 255;
    int jp = tid >> 8;
    int jj = bid * 4 + jp * 2;          // bid-based: covers all 1024 cols
    float p0 = sensor_pos[t*2+0], p1 = sensor_pos[t*2+1];
    float a0 = 0.f, a1 = 0.f;
    for (int r = 0; r < 256; ++r) {
      float pr = p0 * Bm[r] + p1 * Bm[256 + r];
      float sn, cs;
      __sincosf(pr, &sn, &cs);
      a0 += cs * proj_w[r*1024 + jj]     + sn * proj_w[(256+r)*1024 + jj];
      a1 += cs * proj_w[r*1024 + jj + 1] + sn * proj_w[(256+r)*1024 + jj + 1];
    }
    for (int i = 0; i < 3; ++i) {
      float v = sensor_vals[t*3 + i];
      a0 += v * proj_w[(512+i)*1024 + jj];
      a1 += v * proj_w[(512+i)*1024 + jj + 1];
    }
    a0 += proj_b[jj]; a1 += proj_b[jj + 1];
    st_agent(&seq0[t*DMODEL + jj],     a0);
    st_agent(&seq0[t*DMODEL + jj + 1], a1);
    __syncthreads();
    if (tid == 0)
      __hip_atomic_store(&initflags[bid*32], 1, __ATOMIC_RELEASE, __HIP_MEMORY_SCOPE_AGENT);
  }

  // ---------------- phase 1: weights into VGPRs ------------------------------
  // wave w owns cols {j0+2w, j0+2w+1}; lane l owns rows {256q+4l+j}, k=4q+j
  // slab: smem[c*1024 + ((row + 4c) & 1023)] -> writes 2-way (free),
  // reads 4x b128 per col, 64 lanes contiguous (conflict-free, 16B aligned)
  float wx[3][2][16], wh[3][2][16];
  {
    const float* mats[4] = { ff1_w + (size_t)layer*2048*DMODEL,
                             ff2_w + (size_t)layer*2048*DMODEL,
                             ta_w  + (size_t)layer*2048*DMODEL,
                             tb_w  + (size_t)layer*2048*DMODEL };
    #pragma unroll
    for (int ph = 0; ph < 8; ++ph) {    // p = ph>>1 (mat), hf = ph&1 (x/h half)
      const int p  = ph >> 1;
      const int hf = ph & 1;
      __syncthreads();
      const float* W = mats[p];
      for (int i = 0; i < 16; ++i) {
        int f0 = (i*512 + tid) * 2;
        int rl = f0 >> 4;
        int c  = f0 & 15;
        float2 v = *(const float2*)&W[(size_t)(hf*1024 + rl)*DMODEL + j0 + c];
        smem[ c   *1024 + ((rl + 4* c   ) & 1023)] = v.x;
        smem[(c+1)*1024 + ((rl + 4*(c+1)) & 1023)] = v.y;
      }
      __syncthreads();
      #pragma unroll
      for (int cc = 0; cc < 2; ++cc) {
        const int c = 2*w + cc;
        #pragma unroll
        for (int q = 0; q < 4; ++q) {
          int rowbase = (256*q + 4*lane + 4*c) & 1023;
          f32x4 v = *(const f32x4*)&smem[c*1024 + rowbase];
          #pragma unroll
          for (int j = 0; j < 4; ++j) {
            const int k = 4*q + j;
            float vv = v[j];
            if      (ph == 0) wx[0][cc][k] = vv;
            else if (ph == 1) wh[0][cc][k] = vv;
            else if (ph == 2) wx[1][cc][k] = vv;
            else if (ph == 3) wh[1][cc][k] = vv;
            else if (ph == 4) wx[2][cc][k] = -vv;
            else if (ph == 5) wh[2][cc][k] = -vv;
            else if (ph == 6) wx[2][cc][k] += vv;
            else              wh[2][cc][k] += vv;
          }
        }
      }
    }
  }
  float bb1[2], bb2[2], bbc[2];
  #pragma unroll
  for (int cc = 0; cc < 2; ++cc) {
    int j = j0 + 2*w + cc;
    bb1[cc] = ff1_b[layer*DMODEL + j];
    bb2[cc] = ff2_b[layer*DMODEL + j];
    bbc[cc] = tb_b[layer*DMODEL + j] - ta_b[layer*DMODEL + j];
  }

  // ---------------- wait for seq0 (layer 0 only) -----------------------------
  if (layer == 0) {
    if (tid < 64) {
      for (;;) {
        int ok = 1;
        for (int q = 0; q < 4; ++q) {
          int v = __hip_atomic_load(&initflags[(tid + q*64)*32],
                                    __ATOMIC_RELAXED, __HIP_MEMORY_SCOPE_AGENT);
          ok &= (v != 0);
        }
        if (__all(ok)) break;
        if (__builtin_amdgcn_s_memrealtime() - tstart > TIME_CAP) break;
      }
      __threadfence();
    }
  }
  __syncthreads();

  // ---------------- phase 2: wavefront scan, split x/h phases ----------------
  u64* recO = rec + (size_t)layer * KSTEPS * DMODEL;
  u64* recP = rec + (size_t)(layer > 0 ? layer-1 : 0) * KSTEPS * DMODEL;

  for (int t = 0; t < KSTEPS; ++t) {
    const int needH = (t > 0);
    const int needX = (layer > 0);
    const int i0 = tid << 1;
    const u64* pH = recO + (needH ? (size_t)(t-1)*DMODEL : 0) + i0;
    const unsigned sh = (unsigned)t;

    // ---- x phase: gather (1-round slack -> usually first-try), stage -------
    float xva = 0.f, xvb = 0.f;
    if (layer == 0) {
      float2 x2 = *(const float2*)&seq0[(size_t)t*DMODEL + i0];
      xva = x2.x; xvb = x2.y;
    } else {
      const u64* pX = recP + (size_t)t*DMODEL + i0;
      const unsigned sx = (unsigned)(t + 1);
      u64 x0 = 0, x1 = 0;
      int xok = 0, c3 = 0;
      for (;;) {
        x0 = ld_pkt(pX); x1 = ld_pkt(pX + 1);
        xok = ((unsigned)(x0 >> 32) == sx) & ((unsigned)(x1 >> 32) == sx);
        if (__all(xok)) break;
        __builtin_amdgcn_s_sleep(2);
        if (((++c3) & 31) == 0 &&
            __builtin_amdgcn_s_memrealtime() - tstart > TIME_CAP) break;
      }
      xva = __int_as_float((int)(unsigned)x0);
      xvb = __int_as_float((int)(unsigned)x1);
    }
    float* hbuf = smem + (t & 1) * 2048;
    float* xbuf = hbuf + 1024;
    *(float2*)&xbuf[i0] = make_float2(xva, xvb);
    __syncthreads();   // B1: xbuf ready

    // ---- early h probe: loads fly during the x-FMAs ------------------------
    u64 h0 = 0, h1 = 0;
    if (needH) { h0 = ld_pkt(pH); h1 = ld_pkt(pH + 1); }

    // ---- x-FMA (96 fma) while h probe is in flight -------------------------
    float a[3][2] = {};
    #pragma unroll
    for (int q = 0; q < 4; ++q) {
      f32x4 vx = *(const f32x4*)&xbuf[256*q + 4*lane];
      #pragma unroll
      for (int j = 0; j < 4; ++j) {
        const int k = 4*q + j;
        const float xj = vx[j];
        #pragma unroll
        for (int m = 0; m < 3; ++m)
          #pragma unroll
          for (int cc = 0; cc < 2; ++cc)
            a[m][cc] = fmaf(xj, wx[m][cc][k], a[m][cc]);
      }
    }

    // ---- h resolve: check early probe, spin only if stale ------------------
    float hva = 0.f, hvb = 0.f;
    if (needH) {
      int hok = ((unsigned)(h0 >> 32) == sh) & ((unsigned)(h1 >> 32) == sh);
      int c4 = 0;
      while (!__all(hok)) {
        __builtin_amdgcn_s_sleep(2);
        if (!hok) { h0 = ld_pkt(pH); h1 = ld_pkt(pH + 1);
                    hok = ((unsigned)(h0 >> 32) == sh) &
                          ((unsigned)(h1 >> 32) == sh); }
        if (((++c4) & 31) == 0 &&
            __builtin_amdgcn_s_memrealtime() - tstart > TIME_CAP) break;
      }
      hva = __int_as_float((int)(unsigned)h0);
      hvb = __int_as_float((int)(unsigned)h1);
    }
    *(float2*)&hbuf[i0] = make_float2(hva, hvb);
    __syncthreads();   // B2: hbuf ready

    // ---- h-FMA (96 fma): short post-detect tail ----------------------------
    #pragma unroll
    for (int q = 0; q < 4; ++q) {
      f32x4 vh = *(const f32x4*)&hbuf[256*q + 4*lane];
      #pragma unroll
      for (int j = 0; j < 4; ++j) {
        const int k = 4*q + j;
        const float hj = vh[j];
        #pragma unroll
        for (int m = 0; m < 3; ++m)
          #pragma unroll
          for (int cc = 0; cc < 2; ++cc)
            a[m][cc] = fmaf(hj, wh[m][cc][k], a[m][cc]);
      }
    }

    // ---- wave DPP reduce; lane 63 finalizes 2 cols
    float r[3][2];
    #pragma unroll
    for (int m = 0; m < 3; ++m)
      #pragma unroll
      for (int cc = 0; cc < 2; ++cc)
        r[m][cc] = wave_sum64(a[m][cc]);

    if (lane == 63) {
      #pragma unroll
      for (int cc = 0; cc < 2; ++cc) {
        float f1 = tanh_fast(r[0][cc] + bb1[cc]);
        float f2 = tanh_fast(r[1][cc] + bb2[cc]);
        float g  = 1.f / (1.f + __expf(-(r[2][cc] + bbc[cc])));
        float h  = f2 + g * (f1 - f2);
        int j = j0 + 2*w + cc;
        u64 pk = ((u64)(unsigned)(t + 1) << 32) | (unsigned)__float_as_int(h);
        st_pkt(recO + (size_t)t*DMODEL + j, pk);
        if (layer == NLAYER-1 && t == KSTEPS-1) out[j] = h;
      }
    }
    // no trailing barrier: next round uses the other LDS parity
  }
}

extern "C" void kernel_launch(void* const* d_in, const int* in_sizes, int n_in,
                              void* d_out, int out_size, void* d_ws, size_t ws_size,
                              hipStream_t stream) {
  if (ws_size < WS_NEED_BYTES) return;  // informative fail, no fault

  const float* sensor_vals = (const float*)d_in[0];
  const float* sensor_pos  = (const float*)d_in[1];
  const float* Bm          = (const float*)d_in[2];
  const float* proj_w      = (const float*)d_in[3];
  const float* proj_b      = (const float*)d_in[4];
  const float* ff1_w       = (const float*)d_in[5];
  const float* ff1_b       = (const float*)d_in[6];
  const float* ff2_w       = (const float*)d_in[7];
  const float* ff2_b       = (const float*)d_in[8];
  const float* ta_w        = (const float*)d_in[9];
  const float* ta_b        = (const float*)d_in[10];
  const float* tb_w        = (const float*)d_in[11];
  const float* tb_b        = (const float*)d_in[12];
  float* ws        = (float*)d_ws;
  int* initflags   = (int*)(ws + SEQ0_FLOATS);
  u64* rec         = (u64*)(ws + REC_OFF_FLOATS);

  cfc_init<<<1025, 1024, 0, stream>>>(initflags, rec);
  cfc_main<<<256, NTHREADS, 0, stream>>>(sensor_vals, sensor_pos, Bm,
                                         proj_w, proj_b,
                                         ff1_w, ff1_b, ff2_w, ff2_b,
                                         ta_w, ta_b, tb_w, tb_b,
                                         (float*)d_out, ws);
}